// Round 5
// baseline (81.361 us; speedup 1.0000x reference)
//
#include <hip/hip_runtime.h>

constexpr int STRU = 68;   // row stride in u32 (272 B; rows 16B-aligned)

typedef short v8s  __attribute__((ext_vector_type(8)));
typedef float v16f __attribute__((ext_vector_type(16)));

// fp32 -> packed (bf16_hi << 16) | bf16_lo. hi = truncated, lo = Dekker remainder.
__device__ __forceinline__ unsigned packhl(float x) {
    unsigned xb = __builtin_bit_cast(unsigned, x);
    unsigned hb = xb & 0xffff0000u;
    float lof = x - __builtin_bit_cast(float, hb);           // exact
    unsigned lb = __builtin_bit_cast(unsigned, lof) + 0x8000u;
    return __builtin_amdgcn_perm(xb, lb, 0x07060302u);
}

__device__ __forceinline__ float unpackf(unsigned v) {
    float h = __builtin_bit_cast(float, v & 0xffff0000u);
    float l = __builtin_bit_cast(float, v << 16);
    return h + l;
}

// load 8 packed u32 (one MFMA k-fragment of a row) -> hi/lo bf16x8
__device__ __forceinline__ void load_frag(const unsigned* p, v8s& hi, v8s& lo) {
    uint4 a = *(const uint4*)p;
    uint4 b = *(const uint4*)(p + 4);
    uint4 hw, lw;
    hw.x = __builtin_amdgcn_perm(a.y, a.x, 0x07060302u);
    hw.y = __builtin_amdgcn_perm(a.w, a.z, 0x07060302u);
    hw.z = __builtin_amdgcn_perm(b.y, b.x, 0x07060302u);
    hw.w = __builtin_amdgcn_perm(b.w, b.z, 0x07060302u);
    lw.x = __builtin_amdgcn_perm(a.y, a.x, 0x05040100u);
    lw.y = __builtin_amdgcn_perm(a.w, a.z, 0x05040100u);
    lw.z = __builtin_amdgcn_perm(b.y, b.x, 0x05040100u);
    lw.w = __builtin_amdgcn_perm(b.w, b.z, 0x05040100u);
    hi = __builtin_bit_cast(v8s, hw);
    lo = __builtin_bit_cast(v8s, lw);
}

#define MFMA32 __builtin_amdgcn_mfma_f32_32x32x16_bf16

// One 32x32 output tile (tr,tc) of D = P * Q^T over K=64.
// A/B frag: [m = lane&31][k = (lane>>5)*8 + j].  Two accs to shorten dep chain.
__device__ __forceinline__ v16f tile32(const unsigned* __restrict__ P,
                                       const unsigned* __restrict__ Q,
                                       int tr, int tc, int lane) {
    const int r = lane & 31, hh = lane >> 5;
    v16f a0, a1;
    #pragma unroll
    for (int i = 0; i < 16; ++i) { a0[i] = 0.0f; a1[i] = 0.0f; }
    #pragma unroll
    for (int kk = 0; kk < 4; ++kk) {
        const int kc = kk * 16 + hh * 8;
        v8s ph, pl, qh, ql;
        load_frag(P + (tr * 32 + r) * STRU + kc, ph, pl);
        load_frag(Q + (tc * 32 + r) * STRU + kc, qh, ql);
        a0 = MFMA32(ph, qh, a0, 0, 0, 0);
        a1 = MFMA32(ph, ql, a1, 0, 0, 0);
        a1 = MFMA32(pl, qh, a1, 0, 0, 0);
    }
    return a0 + a1;
}

// C/D layout: col = lane&31 (+32*tc), row = (reg&3) + 8*(reg>>2) + 4*(lane>>5) (+32*tr)
__device__ __forceinline__ void store_pk(unsigned* D, int tr, int tc, int lane,
                                         const v16f& a, float sc) {
    const int r = lane & 31, hh = lane >> 5;
    #pragma unroll
    for (int g = 0; g < 4; ++g)
        #pragma unroll
        for (int e = 0; e < 4; ++e) {
            const int row = tr * 32 + 8 * g + 4 * hh + e;
            D[row * STRU + tc * 32 + r] = packhl(sc * a[4 * g + e]);
        }
}

// dual store: D (normal) and DT (transposed, b128 per reg-group)
__device__ __forceinline__ void store_dual(unsigned* D, unsigned* DT, int tr, int tc,
                                           int lane, const v16f& a) {
    const int r = lane & 31, hh = lane >> 5;
    #pragma unroll
    for (int g = 0; g < 4; ++g) {
        uint4 tp;
        #pragma unroll
        for (int e = 0; e < 4; ++e) {
            const int row = tr * 32 + 8 * g + 4 * hh + e;
            unsigned pk = packhl(a[4 * g + e]);
            D[row * STRU + tc * 32 + r] = pk;
            ((unsigned*)&tp)[e] = pk;
        }
        *(uint4*)&DT[(tc * 32 + r) * STRU + tr * 32 + 8 * g + 4 * hh] = tp;
    }
}

__launch_bounds__(512)
__global__ void krylov_kernel(const float* __restrict__ A,
                              const float* __restrict__ Bv,
                              const float* __restrict__ Cv,
                              const float* __restrict__ logdt,
                              float* __restrict__ out)
{
    const int h    = blockIdx.x;
    const int tid  = threadIdx.x;
    const int lane = tid & 63;
    const int w    = tid >> 6;
    const int r    = lane & 31, hh = lane >> 5;

    // 0:S/ping 1:D~/T/pong 2:D2/X 3:D3/XT 4:D4/Vt 5:Ut
    __shared__ __align__(16) unsigned SM[6][64 * STRU];
    __shared__ float Bl[64], tmv[64];

    const float dt = expf(logdt[h]);
    const float c  = 0.5f * dt;
    const float al = 1.0f + 0.5f * c;
    const float sd = -(c * c) / (al * al);   // D~ = sd * (S S^T) = (c^2/a^2) S^2
    const float c1 = 2.0f / al;              // X = c1*T + c2*(S T) - I
    const float c2 = 2.0f * c / (al * al);
    const float k1 = dt / al;                // dB = k1*(T B) + k2*(S (T B))
    const float k2 = dt * c / (al * al);

    const float* Ah = A + (size_t)h * 4096;

    // ---- P0: pack S = A + 0.5I -> SM0; B -> Bl; Ut row0 = C -> SM5 ----
    for (int idx = tid; idx < 1024; idx += 512) {
        const int rr = idx >> 4, c0 = (idx & 15) * 4;
        float4 v = *(const float4*)(Ah + idx * 4);
        if (rr == c0 + 0) v.x += 0.5f;
        if (rr == c0 + 1) v.y += 0.5f;
        if (rr == c0 + 2) v.z += 0.5f;
        if (rr == c0 + 3) v.w += 0.5f;
        uint4 pk = make_uint4(packhl(v.x), packhl(v.y), packhl(v.z), packhl(v.w));
        *(uint4*)&SM[0][rr * STRU + c0] = pk;
    }
    if (tid < 64) Bl[tid] = Bv[h * 64 + tid];
    else if (tid < 128) SM[5][tid - 64] = packhl(Cv[h * 64 + (tid - 64)]);
    __syncthreads();

    // ---- M1: D~ = sd * (S * S^T) -> SM1 ----
    if (w < 4) {
        v16f a = tile32(SM[0], SM[0], w >> 1, w & 1, lane);
        store_pk(SM[1], w >> 1, w & 1, lane, a, sd);
    }
    __syncthreads();
    // ---- M2: D2 = D~ * D~^T -> SM2 (D~ symmetric) ----
    if (w < 4) {
        v16f a = tile32(SM[1], SM[1], w >> 1, w & 1, lane);
        store_pk(SM[2], w >> 1, w & 1, lane, a, 1.0f);
    }
    __syncthreads();
    // ---- M3: D3 = D~ * D2 -> SM3 (waves 0-3); D4 = D2 * D2 -> SM4 (waves 4-7) ----
    if (w < 4) {
        v16f a = tile32(SM[1], SM[2], w >> 1, w & 1, lane);
        store_pk(SM[3], w >> 1, w & 1, lane, a, 1.0f);
    } else {
        const int u = w - 4;
        v16f a = tile32(SM[2], SM[2], u >> 1, u & 1, lane);
        store_pk(SM[4], u >> 1, u & 1, lane, a, 1.0f);
    }
    __syncthreads();
    // ---- E-pass: T = I + D~ + D2 + D3 + D4 -> SM1 (in place, elementwise) ----
    for (int idx = tid; idx < 1024; idx += 512) {
        const int rr = idx >> 4, c0 = (idx & 15) * 4;
        const int ad = rr * STRU + c0;
        uint4 x1 = *(const uint4*)&SM[1][ad];
        uint4 x2 = *(const uint4*)&SM[2][ad];
        uint4 x3 = *(const uint4*)&SM[3][ad];
        uint4 x4 = *(const uint4*)&SM[4][ad];
        float t0 = unpackf(x1.x) + unpackf(x2.x) + unpackf(x3.x) + unpackf(x4.x)
                 + (rr == c0 + 0 ? 1.0f : 0.0f);
        float t1 = unpackf(x1.y) + unpackf(x2.y) + unpackf(x3.y) + unpackf(x4.y)
                 + (rr == c0 + 1 ? 1.0f : 0.0f);
        float t2 = unpackf(x1.z) + unpackf(x2.z) + unpackf(x3.z) + unpackf(x4.z)
                 + (rr == c0 + 2 ? 1.0f : 0.0f);
        float t3 = unpackf(x1.w) + unpackf(x2.w) + unpackf(x3.w) + unpackf(x4.w)
                 + (rr == c0 + 3 ? 1.0f : 0.0f);
        uint4 pk = make_uint4(packhl(t0), packhl(t1), packhl(t2), packhl(t3));
        *(uint4*)&SM[1][ad] = pk;
    }
    __syncthreads();
    // ---- M4: SH = S*T^T (T sym); X = c1*T + c2*SH - I -> SM2, XT -> SM3.
    //      Wave 4 concurrently: dB seed = k1*(T B) + k2*(S (T B)) -> Vt row0 ----
    if (w < 4) {
        const int tr = w >> 1, tc = w & 1;
        v16f a = tile32(SM[0], SM[1], tr, tc, lane);
        #pragma unroll
        for (int g = 0; g < 4; ++g)
            #pragma unroll
            for (int e = 0; e < 4; ++e) {
                const int row = tr * 32 + 8 * g + 4 * hh + e;
                const int col = tc * 32 + r;
                float t  = unpackf(SM[1][row * STRU + col]);
                float dg = (row == col) ? 1.0f : 0.0f;
                float base = c1 * t - dg;
                float sv   = c2 * a[4 * g + e];
                SM[2][row * STRU + col] = packhl(base + sv);
                SM[3][row * STRU + col] = packhl(base - sv);
            }
    } else if (w == 4) {
        // t1 = T*B (row `lane` of symmetric T)
        float acc1 = 0.0f;
        #pragma unroll
        for (int m4 = 0; m4 < 16; ++m4) {
            uint4 tv = *(const uint4*)&SM[1][lane * STRU + 4 * m4];
            float4 b4 = *(const float4*)&Bl[4 * m4];
            acc1 += unpackf(tv.x) * b4.x + unpackf(tv.y) * b4.y
                  + unpackf(tv.z) * b4.z + unpackf(tv.w) * b4.w;
        }
        tmv[lane] = acc1;
        __threadfence_block();                    // wave-local LDS ordering
        float acc2 = 0.0f;
        #pragma unroll
        for (int m4 = 0; m4 < 16; ++m4) {
            uint4 sv = *(const uint4*)&SM[0][lane * STRU + 4 * m4];
            float4 t4 = *(const float4*)&tmv[4 * m4];
            acc2 += unpackf(sv.x) * t4.x + unpackf(sv.y) * t4.y
                  + unpackf(sv.z) * t4.z + unpackf(sv.w) * t4.w;
        }
        SM[4][lane] = packhl(k1 * acc1 + k2 * acc2);   // Vt row 0 = dB
    }
    __syncthreads();

    // ---- ladder A: s=0..5: squaring (waves 0-3, dual store) + V-doubling (4-5) ----
    unsigned *bX = SM[2], *bXT = SM[3], *bN = SM[0], *bNT = SM[1];
    #pragma unroll 1
    for (int s = 0; s < 6; ++s) {
        if (w < 4) {
            v16f a = tile32(bX, bXT, w >> 1, w & 1, lane);
            store_dual(bN, bNT, w >> 1, w & 1, lane, a);
        } else if (w < 6) {
            const int k = 1 << s;
            v16f a = tile32(SM[4], bX, 0, w - 4, lane);   // out[j][m], cols half (w-4)
            #pragma unroll
            for (int g = 0; g < 4; ++g)
                #pragma unroll
                for (int e = 0; e < 4; ++e) {
                    const int j = 8 * g + 4 * hh + e;
                    if (j < k)
                        SM[4][(k + j) * STRU + (w - 4) * 32 + r] = packhl(a[4 * g + e]);
                }
        }
        __syncthreads();
        unsigned* t0 = bX;  bX  = bN;  bN  = t0;
        t0 = bXT; bXT = bNT; bNT = t0;
    }
    // bX = E = dA^64, bXT = E^T

    // ---- ladder B: s=0..5: U-doubling with bXT; dual-squaring while s<5 ----
    #pragma unroll 1
    for (int s = 0; s < 6; ++s) {
        if (w < 4 && s < 5) {
            v16f a = tile32(bX, bXT, w >> 1, w & 1, lane);
            store_dual(bN, bNT, w >> 1, w & 1, lane, a);
        } else if (w >= 4 && w < 6) {
            const int k = 1 << s;
            v16f a = tile32(SM[5], bXT, 0, w - 4, lane);
            #pragma unroll
            for (int g = 0; g < 4; ++g)
                #pragma unroll
                for (int e = 0; e < 4; ++e) {
                    const int j = 8 * g + 4 * hh + e;
                    if (j < k)
                        SM[5][(k + j) * STRU + (w - 4) * 32 + r] = packhl(a[4 * g + e]);
                }
        }
        __syncthreads();
        if (s < 5) {
            unsigned* t0 = bX;  bX  = bN;  bN  = t0;
            t0 = bXT; bXT = bNT; bNT = t0;
        }
    }

    // ---- final: out[h][64q + r'] = sum_n Ut[q][n] * Vt[r'][n] ----
    if (w < 4) {
        const int tr = w >> 1, tc = w & 1;
        v16f a = tile32(SM[5], SM[4], tr, tc, lane);
        float* oh = out + (size_t)h * 4096;
        #pragma unroll
        for (int g = 0; g < 4; ++g)
            #pragma unroll
            for (int e = 0; e < 4; ++e) {
                const int row = tr * 32 + 8 * g + 4 * hh + e;
                oh[row * 64 + tc * 32 + r] = a[4 * g + e];
            }
    }
}

extern "C" void kernel_launch(void* const* d_in, const int* in_sizes, int n_in,
                              void* d_out, int out_size, void* d_ws, size_t ws_size,
                              hipStream_t stream) {
    const float* A  = (const float*)d_in[0];
    const float* B  = (const float*)d_in[1];
    const float* C  = (const float*)d_in[2];
    const float* ld = (const float*)d_in[3];
    float* out = (float*)d_out;
    const int H = in_sizes[3];   // 256 heads
    krylov_kernel<<<H, 512, 0, stream>>>(A, B, C, ld, out);
}